// Round 10
// baseline (267.326 us; speedup 1.0000x reference)
//
#include <hip/hip_runtime.h>
#include <math.h>

// B=4, C=64, H=W=64 -> N=4096. fp32 in/out; fp16 MFMA internally.
// R10: single fused kernel (qkv -> attn -> combine) with SOFTWARE grid
// barriers (device-scope atomic counters in ws, zeroed via hipMemsetAsync).
// R9's hipLaunchCooperativeKernel silently failed -> never again.
// Residency safety: grid 512 blocks; capacity 1024 (LDS 18.4KB -> 8/CU,
// VGPR<=128 -> 4/CU binding) = 2x margin, all blocks resident at launch.
#define T_N 4096
#define T_C 64
#define T_B 4
#define NSLICE 2
#define TILES_PER_SLICE (64 / NSLICE)
#define NBLOCKS 512

typedef __attribute__((ext_vector_type(8))) _Float16 f16x8;  // 4 VGPRs
typedef __attribute__((ext_vector_type(4))) _Float16 f16x4;  // 2 VGPRs
typedef __attribute__((ext_vector_type(4))) float f32x4;     // MFMA acc

__device__ inline unsigned short f2h(float f) {
    union { _Float16 h; unsigned short s; } u; u.h = (_Float16)f; return u.s;
}
__device__ inline float h2f(unsigned short s) {
    union { unsigned short s; _Float16 h; } u; u.s = s; return (float)u.h;
}

__device__ inline void grid_barrier(unsigned int* cnt) {
    __syncthreads();
    if (threadIdx.x == 0) {
        __threadfence();                       // writes visible device-wide
        atomicAdd(cnt, 1u);                    // device-scope by default
        while (__hip_atomic_load(cnt, __ATOMIC_ACQUIRE,
                                 __HIP_MEMORY_SCOPE_AGENT) < NBLOCKS) {
            __builtin_amdgcn_s_sleep(2);
        }
    }
    __syncthreads();
}

// LDS (18,432 B union):
//  Phase A: xsh[32*72] + xsl[32*72] shorts (x^T hi/lo, then bounce buffers)
//  Phase B: ks[64*72] + vs[64*72] shorts
//  Phase C: wn[NSLICE][32] floats
__global__ __launch_bounds__(256, 4) void fused_kernel(
    const float* __restrict__ x,
    const float* __restrict__ Wq, const float* __restrict__ bq,
    const float* __restrict__ Wk, const float* __restrict__ bk,
    const float* __restrict__ Wv, const float* __restrict__ bv,
    unsigned short* __restrict__ qt_hi, unsigned short* __restrict__ qt_lo,
    unsigned short* __restrict__ kt, unsigned short* __restrict__ vb,
    unsigned short* __restrict__ o_part, float* __restrict__ mp,
    float* __restrict__ lp, unsigned int* __restrict__ bars,
    float* __restrict__ out)
{
    __shared__ __align__(16) unsigned short smem[9216];   // 18,432 B

    const int tid  = threadIdx.x;
    const int bid  = blockIdx.x;          // 0..511
    const int wv_  = tid >> 6;
    const int lane = tid & 63;
    const int quad = lane >> 4;
    const int col  = lane & 15;

    // ======================= PHASE A: QKV projection =======================
    // 512 blocks: b = bid>>7, 32-pixel tile n0 = (bid&127)*32.
    // A = x^T hi/lo fp16 (LDS); B = W fragments read DIRECTLY from global
    // (coalesced 1KB/wave, L2-hot) and converted to fp16 in-register.
    // Wave wv_: pixel subtile pst=(wv_&1)*16, osub pair oh=(wv_>>1)*2.
    {
        unsigned short* xsh = smem;           // 32*72
        unsigned short* xsl = smem + 2304;    // 32*72

        const int b  = bid >> 7;
        const int n0 = (bid & 127) * 32;
        const float* xb = x + (size_t)b * T_C * T_N;
        const size_t bN = (size_t)b * T_N;

        for (int i = tid; i < 512; i += 256) {   // 64c x 8 px-chunks
            const int c = i >> 3, px4 = (i & 7) * 4;
            const float4 xv = *(const float4*)&xb[c * T_N + n0 + px4];
            const float xa[4] = {xv.x, xv.y, xv.z, xv.w};
            #pragma unroll
            for (int j = 0; j < 4; ++j) {
                const unsigned short h = f2h(xa[j]);
                xsh[(px4 + j) * 72 + c] = h;
                xsl[(px4 + j) * 72 + c] = f2h(xa[j] - h2f(h));
            }
        }
        __syncthreads();

        const int pst = (wv_ & 1) * 16;
        const int oh  = (wv_ >> 1) * 2;

        f16x8 xh[2], xl[2];   // A[m=px][k=c], m=col -> px = pst+col
        #pragma unroll
        for (int s = 0; s < 2; ++s) {
            xh[s] = *(const f16x8*)&xsh[(pst + col) * 72 + s * 32 + quad * 8];
            xl[s] = *(const f16x8*)&xsl[(pst + col) * 72 + s * 32 + quad * 8];
        }
        __syncthreads();   // frags in regs; xsh/xsl reusable as bounce

        const float* Ws[3]     = {Wq, Wk, Wv};
        const float* biases[3] = {bq, bk, bv};
        for (int p = 0; p < 3; ++p) {
            #pragma unroll
            for (int oo = 0; oo < 2; ++oo) {
                const int osub = oh + oo;
                f32x4 acc = (f32x4){0.f, 0.f, 0.f, 0.f};
                #pragma unroll
                for (int s = 0; s < 2; ++s) {
                    // B[k=c][n=o]: o = osub*16+col, k = s*32+quad*8..+8
                    const float* wrow = Ws[p] + (osub * 16 + col) * 64 + s * 32 + quad * 8;
                    const float4 wa = *(const float4*)&wrow[0];
                    const float4 wb = *(const float4*)&wrow[4];
                    f16x8 wfr;
                    wfr[0] = (_Float16)wa.x; wfr[1] = (_Float16)wa.y;
                    wfr[2] = (_Float16)wa.z; wfr[3] = (_Float16)wa.w;
                    wfr[4] = (_Float16)wb.x; wfr[5] = (_Float16)wb.y;
                    wfr[6] = (_Float16)wb.z; wfr[7] = (_Float16)wb.w;
                    acc = __builtin_amdgcn_mfma_f32_16x16x32_f16(xh[s], wfr, acc, 0, 0, 0);
                    acc = __builtin_amdgcn_mfma_f32_16x16x32_f16(xl[s], wfr, acc, 0, 0, 0);
                }
                // acc[r]: px = pst+quad*4+r, o = osub*16+col
                const float bb = biases[p][osub * 16 + col];
                if (p == 0) {           // Q hi/lo bounce [px][o] pitch 72
                    #pragma unroll
                    for (int r = 0; r < 4; ++r) {
                        const float f = acc[r] + bb;
                        const unsigned short h = f2h(f);
                        const int a = (pst + quad * 4 + r) * 72 + osub * 16 + col;
                        xsh[a] = h;
                        xsl[a] = f2h(f - h2f(h));
                    }
                } else if (p == 1) {    // K bounce [px][o] pitch 72
                    #pragma unroll
                    for (int r = 0; r < 4; ++r)
                        xsh[(pst + quad * 4 + r) * 72 + osub * 16 + col] = f2h(acc[r] + bb);
                } else {                // V bounce [o][px] pitch 36
                    union { ushort4 v; unsigned short s[4]; } hv;
                    #pragma unroll
                    for (int r = 0; r < 4; ++r) hv.s[r] = f2h(acc[r] + bb);
                    *(ushort4*)&xsh[(osub * 16 + col) * 36 + pst + quad * 4] = hv.v;
                }
            }
            __syncthreads();
            if (p == 0) {           // 32px x 64c: one f16x8/thread
                const int pix = tid >> 3, c8 = (tid & 7) * 8;
                *(f16x8*)&qt_hi[(bN + n0 + pix) * 64 + c8] = *(const f16x8*)&xsh[pix * 72 + c8];
                *(f16x8*)&qt_lo[(bN + n0 + pix) * 64 + c8] = *(const f16x8*)&xsl[pix * 72 + c8];
                __syncthreads();
            } else if (p == 1) {
                const int pix = tid >> 3, c8 = (tid & 7) * 8;
                *(f16x8*)&kt[(bN + n0 + pix) * 64 + c8] = *(const f16x8*)&xsh[pix * 72 + c8];
                __syncthreads();
            } else {                // V: 64c x 32px
                const int o = tid >> 2, p8 = (tid & 3) * 8;
                *(f16x8*)&vb[((size_t)(b * 64 + o)) * T_N + n0 + p8] =
                    *(const f16x8*)&xsh[o * 36 + p8];
            }
        }
    }

    grid_barrier(&bars[0]);

    // ==================== PHASE B: flash-attention partial ====================
    // bid -> qtile = bid&63, slice = (bid>>6)&1, b = bid>>7.
    {
        unsigned short* ks = smem;          // [key][ch], pitch 72
        unsigned short* vs = smem + 4608;   // [ch][key], pitch 72

        const int n0    = (bid & 63) * 64;
        const int slice = (bid >> 6) & 1;
        const int b     = bid >> 7;
        const size_t bN = (size_t)b * T_N;
        const int q_own = n0 + wv_ * 16 + col;

        f16x8 qh[2], ql[2];   // B[k=ch][n=q]
        #pragma unroll
        for (int s = 0; s < 2; ++s) {
            const size_t qoff = (bN + q_own) * 64 + s * 32 + quad * 8;
            qh[s] = *(const f16x8*)&qt_hi[qoff];
            ql[s] = *(const f16x8*)&qt_lo[qoff];
        }

        f32x4 O[4];
        #pragma unroll
        for (int t = 0; t < 4; ++t) O[t] = (f32x4){0.f, 0.f, 0.f, 0.f};
        float m_st = -INFINITY, l_st = 0.f;

        for (int it = 0; it < TILES_PER_SLICE; ++it) {
            const int m0 = (slice * TILES_PER_SLICE + it) * 64;
            __syncthreads();
            for (int i = tid; i < 1024; i += 256) {
                if (i < 512) {
                    const int row = i >> 3, cc = i & 7;
                    *(float4*)&ks[row * 72 + cc * 8] =
                        *(const float4*)&kt[(bN + m0 + row) * 64 + cc * 8];
                } else {
                    const int j = i - 512, row = j >> 3, cc = j & 7;
                    *(float4*)&vs[row * 72 + cc * 8] =
                        *(const float4*)&vb[((size_t)(b * 64 + row)) * T_N + m0 + cc * 8];
                }
            }
            __syncthreads();

            // S^T = K Q^T: acc[t] = S^T[key=16t+quad*4+r][q=col]
            f32x4 acc[4];
            #pragma unroll
            for (int t = 0; t < 4; ++t) acc[t] = (f32x4){0.f, 0.f, 0.f, 0.f};
            #pragma unroll
            for (int s = 0; s < 2; ++s) {
                #pragma unroll
                for (int t = 0; t < 4; ++t) {
                    const f16x8 kf =
                        *(const f16x8*)&ks[(t * 16 + col) * 72 + s * 32 + quad * 8];
                    acc[t] = __builtin_amdgcn_mfma_f32_16x16x32_f16(kf, qh[s], acc[t], 0, 0, 0);
                    acc[t] = __builtin_amdgcn_mfma_f32_16x16x32_f16(kf, ql[s], acc[t], 0, 0, 0);
                }
            }

            // online softmax: row = q = col; cross-quad reduce only
            float mx = -INFINITY;
            #pragma unroll
            for (int t = 0; t < 4; ++t)
                #pragma unroll
                for (int r = 0; r < 4; ++r) mx = fmaxf(mx, acc[t][r]);
            mx = fmaxf(mx, __shfl_xor(mx, 16));
            mx = fmaxf(mx, __shfl_xor(mx, 32));
            const float mnew = fmaxf(m_st, mx);
            const float alpha = __expf(m_st - mnew);
            float sum = 0.f;
            f16x4 pf[4];
            #pragma unroll
            for (int t = 0; t < 4; ++t) {
                #pragma unroll
                for (int r = 0; r < 4; ++r) {
                    const float pv = __expf(acc[t][r] - mnew);
                    sum += pv;
                    pf[t][r] = (_Float16)pv;
                }
            }
            sum += __shfl_xor(sum, 16);
            sum += __shfl_xor(sum, 32);
            l_st = alpha * l_st + sum;
            m_st = mnew;

            // O = alpha*O + V P^T (P in registers, B-operand of 16x16x16)
            #pragma unroll
            for (int tc = 0; tc < 4; ++tc) {
                O[tc] *= alpha;
                #pragma unroll
                for (int t = 0; t < 4; ++t) {
                    const f16x4 vf =
                        *(const f16x4*)&vs[(tc * 16 + col) * 72 + t * 16 + quad * 4];
                    O[tc] = __builtin_amdgcn_mfma_f32_16x16x16f16(vf, pf[t], O[tc], 0, 0, 0);
                }
            }
        }

        // epilogue: c = tc*16+quad*4+r, q = col
        #pragma unroll
        for (int tc = 0; tc < 4; ++tc) {
            #pragma unroll
            for (int r = 0; r < 4; ++r) {
                o_part[((size_t)((slice * T_B + b) * 64 + tc * 16 + quad * 4 + r)) * T_N +
                       q_own] = f2h(O[tc][r]);
            }
        }
        if (quad == 0) {
            const size_t off = (size_t)(slice * T_B + b) * T_N + q_own;
            mp[off] = m_st;
            lp[off] = l_st;
        }
    }

    grid_barrier(&bars[1]);

    // ========================= PHASE C: combine =========================
    // bid -> b = bid>>7, 32-pixel tile n0 = (bid&127)*32.
    {
        float* wn = (float*)smem;   // [NSLICE][32]

        const int b  = bid >> 7;
        const int n0 = (bid & 127) * 32;

        if (tid < 32) {
            float m_s[NSLICE], l_s[NSLICE];
            #pragma unroll
            for (int s = 0; s < NSLICE; ++s) {
                const size_t off = (size_t)(s * T_B + b) * T_N + n0 + tid;
                m_s[s] = mp[off];
                l_s[s] = lp[off];
            }
            float M = m_s[0];
            #pragma unroll
            for (int s = 1; s < NSLICE; ++s) M = fmaxf(M, m_s[s]);
            float w_s[NSLICE], L = 0.f;
            #pragma unroll
            for (int s = 0; s < NSLICE; ++s) {
                w_s[s] = __expf(m_s[s] - M);
                L += l_s[s] * w_s[s];
            }
            const float inv = 1.f / L;
            #pragma unroll
            for (int s = 0; s < NSLICE; ++s) wn[s * 32 + tid] = w_s[s] * inv;
        }
        __syncthreads();

        for (int t = tid; t < 512; t += 256) {
            const int c = t >> 3, g = t & 7;
            float4 acc = make_float4(0.f, 0.f, 0.f, 0.f);
            #pragma unroll
            for (int s = 0; s < NSLICE; ++s) {
                const ushort4 o4 = *(const ushort4*)
                    &o_part[((size_t)((s * T_B + b) * 64 + c)) * T_N + n0 + g * 4];
                acc.x = fmaf(h2f(o4.x), wn[s * 32 + g * 4 + 0], acc.x);
                acc.y = fmaf(h2f(o4.y), wn[s * 32 + g * 4 + 1], acc.y);
                acc.z = fmaf(h2f(o4.z), wn[s * 32 + g * 4 + 2], acc.z);
                acc.w = fmaf(h2f(o4.w), wn[s * 32 + g * 4 + 3], acc.w);
            }
            *(float4*)&out[((size_t)(b * 64 + c)) * T_N + n0 + g * 4] = acc;
        }
    }
}

// ---------------------------------------------------------------------------
extern "C" void kernel_launch(void* const* d_in, const int* in_sizes, int n_in,
                              void* d_out, int out_size, void* d_ws, size_t ws_size,
                              hipStream_t stream) {
    const float* x  = (const float*)d_in[0];
    const float* Wq = (const float*)d_in[1];
    const float* bq = (const float*)d_in[2];
    const float* Wk = (const float*)d_in[3];
    const float* bk = (const float*)d_in[4];
    const float* Wv = (const float*)d_in[5];
    const float* bv = (const float*)d_in[6];
    float* outp = (float*)d_out;

    // ws: [bars: 2 uint (16B pad)] qt_hi/qt_lo/kt/vb (4 x 2MB) +
    //     o_part (NSLICE x 2MB) + mp/lp (2 x 128KB)
    unsigned int* bars = (unsigned int*)d_ws;
    const size_t elems = (size_t)T_B * T_N * T_C;
    unsigned short* qt_hi  = (unsigned short*)((char*)d_ws + 16);
    unsigned short* qt_lo  = qt_hi + elems;
    unsigned short* ktp    = qt_lo + elems;
    unsigned short* vbuf   = ktp + elems;
    unsigned short* o_part = vbuf + elems;
    float* mp = (float*)(o_part + (size_t)NSLICE * elems);
    float* lp = mp + (size_t)NSLICE * T_B * T_N;

    hipMemsetAsync(bars, 0, 8, stream);   // reset barrier counters (capture-safe)
    fused_kernel<<<dim3(NBLOCKS), dim3(256), 0, stream>>>(
        x, Wq, bq, Wk, bk, Wv, bv, qt_hi, qt_lo, ktp, vbuf,
        o_part, mp, lp, bars, outp);
}

// Round 11
// 151.713 us; speedup vs baseline: 1.7620x; 1.7620x over previous
//
#include <hip/hip_runtime.h>
#include <math.h>

// B=4, C=64, H=W=64 -> N=4096. fp32 in/out; fp16 MFMA internally.
// R10 post-mortem: ~68us of total is FIXED timed harness overhead (measured
// with a single-dispatch kernel). R7 3-kernel structure restored.
// R11: (1) single-fp16 Q (no hi/lo): S-MFMAs 16->8/tile; logit err ~0.0055
//      -> absmax ~0.05 predicted (threshold 0.1025).
//      (2) software-pipelined K/V staging: global->reg prefetch of tile i+1
//      issued after the barrier, consumed next iter -> latency hidden under
//      compute; only ds_write_b128 sits between barriers.
#define T_N 4096
#define T_C 64
#define T_B 4
#define NSLICE 4
#define TILES_PER_SLICE (64 / NSLICE)

typedef __attribute__((ext_vector_type(8))) _Float16 f16x8;  // 4 VGPRs
typedef __attribute__((ext_vector_type(4))) _Float16 f16x4;  // 2 VGPRs
typedef __attribute__((ext_vector_type(4))) float f32x4;     // MFMA acc

__device__ inline unsigned short f2h(float f) {
    union { _Float16 h; unsigned short s; } u; u.h = (_Float16)f; return u.s;
}
__device__ inline float h2f(unsigned short s) {
    union { unsigned short s; _Float16 h; } u; u.s = s; return (float)u.h;
}

// ---------------------------------------------------------------------------
// Kernel 1: fused QKV projection via MFMA (R7 structure, qt_lo removed).
// grid (N/32, B) = 512 blocks, 256 thr (4 waves). LDS: x^T hi/lo + 3 W fp16.
//   qt, kt: (B,N,C) fp16;  vb: (B,C,N) fp16
// ---------------------------------------------------------------------------
__global__ __launch_bounds__(256) void qkv_kernel(
    const float* __restrict__ x,
    const float* __restrict__ Wq, const float* __restrict__ bq,
    const float* __restrict__ Wk, const float* __restrict__ bk,
    const float* __restrict__ Wv, const float* __restrict__ bv,
    unsigned short* __restrict__ qt, unsigned short* __restrict__ kt,
    unsigned short* __restrict__ vb)
{
    __shared__ __align__(16) unsigned short xsh[32 * 72];   // x^T hi / bounce
    __shared__ __align__(16) unsigned short xsl[32 * 72];   // x^T lo
    __shared__ __align__(16) unsigned short wf[3][64 * 72]; // W fp16 [o][c]

    const int tid = threadIdx.x;
    const int n0  = blockIdx.x * 32;
    const int b   = blockIdx.y;
    const float* xb = x + (size_t)b * T_C * T_N;

    const float* Ws[3] = {Wq, Wk, Wv};
    #pragma unroll
    for (int p = 0; p < 3; ++p) {
        for (int i = tid; i < 1024; i += 256) {
            const int o = i >> 4, c4 = (i & 15) * 4;
            const float4 w4 = ((const float4*)Ws[p])[i];
            f16x4 wh;
            wh[0] = (_Float16)w4.x; wh[1] = (_Float16)w4.y;
            wh[2] = (_Float16)w4.z; wh[3] = (_Float16)w4.w;
            *(f16x4*)&wf[p][o * 72 + c4] = wh;
        }
    }
    for (int i = tid; i < 512; i += 256) {
        const int c = i >> 3, nj4 = (i & 7) * 4;
        const float4 xv = *(const float4*)&xb[c * T_N + n0 + nj4];
        const float xa[4] = {xv.x, xv.y, xv.z, xv.w};
        #pragma unroll
        for (int j = 0; j < 4; ++j) {
            const unsigned short h = f2h(xa[j]);
            xsh[(nj4 + j) * 72 + c] = h;
            xsl[(nj4 + j) * 72 + c] = f2h(xa[j] - h2f(h));
        }
    }
    __syncthreads();

    const int wv_  = tid >> 6;
    const int lane = tid & 63;
    const int quad = lane >> 4;
    const int col  = lane & 15;
    const int pst  = (wv_ & 1) * 16;      // pixel subtile base (0 or 16)
    const int oh   = (wv_ >> 1) * 2;      // osub base (0 or 2)
    const size_t bN = (size_t)b * T_N;

    f16x8 xh[2], xl[2];   // A[m=px][k=c]: m=col -> px = pst+col
    #pragma unroll
    for (int s = 0; s < 2; ++s) {
        xh[s] = *(const f16x8*)&xsh[(pst + col) * 72 + s * 32 + quad * 8];
        xl[s] = *(const f16x8*)&xsl[(pst + col) * 72 + s * 32 + quad * 8];
    }
    __syncthreads();   // frags in regs; xsh reusable as bounce

    const float* biases[3] = {bq, bk, bv};
    for (int p = 0; p < 3; ++p) {
        #pragma unroll
        for (int oo = 0; oo < 2; ++oo) {
            const int osub = oh + oo;
            f32x4 acc = (f32x4){0.f, 0.f, 0.f, 0.f};
            #pragma unroll
            for (int s = 0; s < 2; ++s) {
                const f16x8 wfr =   // B[k=c][n=o]: o = osub*16+col
                    *(const f16x8*)&wf[p][(osub * 16 + col) * 72 + s * 32 + quad * 8];
                acc = __builtin_amdgcn_mfma_f32_16x16x32_f16(xh[s], wfr, acc, 0, 0, 0);
                acc = __builtin_amdgcn_mfma_f32_16x16x32_f16(xl[s], wfr, acc, 0, 0, 0);
            }
            // acc[r]: px = pst+quad*4+r, o = osub*16+col
            const float bb = biases[p][osub * 16 + col];
            if (p < 2) {            // Q/K bounce [px][o] pitch 72
                #pragma unroll
                for (int r = 0; r < 4; ++r)
                    xsh[(pst + quad * 4 + r) * 72 + osub * 16 + col] = f2h(acc[r] + bb);
            } else {                // V bounce [o][px] pitch 36
                union { ushort4 v; unsigned short s[4]; } hv;
                #pragma unroll
                for (int r = 0; r < 4; ++r) hv.s[r] = f2h(acc[r] + bb);
                *(ushort4*)&xsh[(osub * 16 + col) * 36 + pst + quad * 4] = hv.v;
            }
        }
        __syncthreads();
        if (p < 2) {            // 32px x 64c: one f16x8/thread, coalesced
            const int pix = tid >> 3, c8 = (tid & 7) * 8;
            unsigned short* dst = (p == 0) ? qt : kt;
            *(f16x8*)&dst[(bN + n0 + pix) * 64 + c8] = *(const f16x8*)&xsh[pix * 72 + c8];
            __syncthreads();
        } else {                // V: 64c x 32px
            const int o = tid >> 2, p8 = (tid & 3) * 8;
            *(f16x8*)&vb[((size_t)(b * 64 + o)) * T_N + n0 + p8] =
                *(const f16x8*)&xsh[o * 36 + p8];
        }
    }
}

// ---------------------------------------------------------------------------
// Kernel 2: flash-attention partial over one key-slice.
// grid (64, NSLICE, B) = 1024 blocks, 256 thr (4 waves), LDS 18.4 KB ->
// 4 blocks/CU (16 waves/CU). S^T = K*Q^T, single-fp16 Q (8 MFMAs/tile);
// per-lane softmax state; P^T in registers as B-operand of 16x16x16 f16.
// K/V staging software-pipelined: tile i+1 global->reg during tile-i compute.
// ---------------------------------------------------------------------------
__global__ __launch_bounds__(256, 4) void attn_kernel(
    const unsigned short* __restrict__ qt,
    const unsigned short* __restrict__ kt, const unsigned short* __restrict__ vb,
    unsigned short* __restrict__ o_part, float* __restrict__ mp, float* __restrict__ lp)
{
    __shared__ __align__(16) unsigned short ks[64 * 72];   // [key][ch]
    __shared__ __align__(16) unsigned short vs[64 * 72];   // [ch][key]

    const int tid   = threadIdx.x;
    const int n0    = blockIdx.x * 64;
    const int slice = blockIdx.y;
    const int b     = blockIdx.z;
    const int wv_   = tid >> 6;
    const int lane  = tid & 63;
    const int quad  = lane >> 4;
    const int col   = lane & 15;

    const size_t bN = (size_t)b * T_N;
    const int q_own = n0 + wv_ * 16 + col;   // this lane's query

    f16x8 qh[2];   // B[k=ch][n=q]: n=col -> q_own
    #pragma unroll
    for (int s = 0; s < 2; ++s)
        qh[s] = *(const f16x8*)&qt[(bN + q_own) * 64 + s * 32 + quad * 8];

    // staging map: this thread stages ks rows {row, row+32} chunk cc and
    // vs rows {row, row+32} chunk cc (float4 = 8 fp16)
    const int row = tid >> 3, cc = tid & 7;

    // prefetch tile 0 into registers
    float4 pre[4];
    {
        const int m0 = slice * TILES_PER_SLICE * 64;
        pre[0] = *(const float4*)&kt[(bN + m0 + row) * 64 + cc * 8];
        pre[1] = *(const float4*)&kt[(bN + m0 + 32 + row) * 64 + cc * 8];
        pre[2] = *(const float4*)&vb[((size_t)(b * 64 + row)) * T_N + m0 + cc * 8];
        pre[3] = *(const float4*)&vb[((size_t)(b * 64 + 32 + row)) * T_N + m0 + cc * 8];
    }

    f32x4 O[4];
    #pragma unroll
    for (int t = 0; t < 4; ++t) O[t] = (f32x4){0.f, 0.f, 0.f, 0.f};
    float m_st = -INFINITY, l_st = 0.f;

    for (int it = 0; it < TILES_PER_SLICE; ++it) {
        __syncthreads();   // previous iteration's ks/vs reads done
        *(float4*)&ks[row * 72 + cc * 8]        = pre[0];
        *(float4*)&ks[(32 + row) * 72 + cc * 8] = pre[1];
        *(float4*)&vs[row * 72 + cc * 8]        = pre[2];
        *(float4*)&vs[(32 + row) * 72 + cc * 8] = pre[3];
        __syncthreads();

        if (it + 1 < TILES_PER_SLICE) {   // issue next tile's loads now;
            const int m0n = (slice * TILES_PER_SLICE + it + 1) * 64;   // hidden under compute
            pre[0] = *(const float4*)&kt[(bN + m0n + row) * 64 + cc * 8];
            pre[1] = *(const float4*)&kt[(bN + m0n + 32 + row) * 64 + cc * 8];
            pre[2] = *(const float4*)&vb[((size_t)(b * 64 + row)) * T_N + m0n + cc * 8];
            pre[3] = *(const float4*)&vb[((size_t)(b * 64 + 32 + row)) * T_N + m0n + cc * 8];
        }

        // --- S^T = K Q^T: acc[t] = S^T[key=16t+quad*4+r][q=col] ---
        f32x4 acc[4];
        #pragma unroll
        for (int t = 0; t < 4; ++t) acc[t] = (f32x4){0.f, 0.f, 0.f, 0.f};
        #pragma unroll
        for (int s = 0; s < 2; ++s) {
            #pragma unroll
            for (int t = 0; t < 4; ++t) {
                const f16x8 kf =   // A[m=key][k=ch]: m=col -> key = 16t+col
                    *(const f16x8*)&ks[(t * 16 + col) * 72 + s * 32 + quad * 8];
                acc[t] = __builtin_amdgcn_mfma_f32_16x16x32_f16(kf, qh[s], acc[t], 0, 0, 0);
            }
        }

        // --- online softmax: row = q = col; cross-quad reduce only ---
        float mx = -INFINITY;
        #pragma unroll
        for (int t = 0; t < 4; ++t)
            #pragma unroll
            for (int r = 0; r < 4; ++r) mx = fmaxf(mx, acc[t][r]);
        mx = fmaxf(mx, __shfl_xor(mx, 16));
        mx = fmaxf(mx, __shfl_xor(mx, 32));
        const float mnew = fmaxf(m_st, mx);
        const float alpha = __expf(m_st - mnew);
        float sum = 0.f;
        f16x4 pf[4];
        #pragma unroll
        for (int t = 0; t < 4; ++t) {
            #pragma unroll
            for (int r = 0; r < 4; ++r) {
                const float pv = __expf(acc[t][r] - mnew);
                sum += pv;
                pf[t][r] = (_Float16)pv;   // B[k=key=16t+quad*4+r][n=q=col]
            }
        }
        sum += __shfl_xor(sum, 16);
        sum += __shfl_xor(sum, 32);
        l_st = alpha * l_st + sum;
        m_st = mnew;

        // --- O = alpha*O + V P^T via 16x16x16 MFMA (P in registers) ---
        #pragma unroll
        for (int tc = 0; tc < 4; ++tc) {
            O[tc] *= alpha;
            #pragma unroll
            for (int t = 0; t < 4; ++t) {
                const f16x4 vf =   // A[m=c][k=key]: m=col -> c = tc*16+col
                    *(const f16x4*)&vs[(tc * 16 + col) * 72 + t * 16 + quad * 4];
                O[tc] = __builtin_amdgcn_mfma_f32_16x16x16f16(vf, pf[t], O[tc], 0, 0, 0);
            }
        }
    }

    // --- epilogue: O[tc][r]: c = tc*16+quad*4+r, q = col ---
    #pragma unroll
    for (int tc = 0; tc < 4; ++tc) {
        #pragma unroll
        for (int r = 0; r < 4; ++r) {
            o_part[((size_t)((slice * T_B + b) * 64 + tc * 16 + quad * 4 + r)) * T_N +
                   q_own] = f2h(O[tc][r]);
        }
    }
    if (quad == 0) {
        const size_t off = (size_t)(slice * T_B + b) * T_N + q_own;
        mp[off] = m_st;
        lp[off] = l_st;
    }
}

// ---------------------------------------------------------------------------
// Kernel 3: combine slices. grid (N/32, B), 256 thr. Pure streaming.
// ---------------------------------------------------------------------------
__global__ __launch_bounds__(256) void combine_kernel(
    const unsigned short* __restrict__ o_part,
    const float* __restrict__ mp, const float* __restrict__ lp,
    float* __restrict__ out)
{
    __shared__ float wn[NSLICE][32];

    const int tid = threadIdx.x;
    const int n0  = blockIdx.x * 32;
    const int b   = blockIdx.y;

    if (tid < 32) {
        float m_s[NSLICE], l_s[NSLICE];
        #pragma unroll
        for (int s = 0; s < NSLICE; ++s) {
            const size_t off = (size_t)(s * T_B + b) * T_N + n0 + tid;
            m_s[s] = mp[off];
            l_s[s] = lp[off];
        }
        float M = m_s[0];
        #pragma unroll
        for (int s = 1; s < NSLICE; ++s) M = fmaxf(M, m_s[s]);
        float w_s[NSLICE], L = 0.f;
        #pragma unroll
        for (int s = 0; s < NSLICE; ++s) {
            w_s[s] = __expf(m_s[s] - M);
            L += l_s[s] * w_s[s];
        }
        const float inv = 1.f / L;
        #pragma unroll
        for (int s = 0; s < NSLICE; ++s) wn[s][tid] = w_s[s] * inv;
    }
    __syncthreads();

    for (int t = tid; t < 512; t += 256) {
        const int c = t >> 3, g = t & 7;
        float4 acc = make_float4(0.f, 0.f, 0.f, 0.f);
        #pragma unroll
        for (int s = 0; s < NSLICE; ++s) {
            const ushort4 o4 = *(const ushort4*)
                &o_part[((size_t)((s * T_B + b) * 64 + c)) * T_N + n0 + g * 4];
            acc.x = fmaf(h2f(o4.x), wn[s][g * 4 + 0], acc.x);
            acc.y = fmaf(h2f(o4.y), wn[s][g * 4 + 1], acc.y);
            acc.z = fmaf(h2f(o4.z), wn[s][g * 4 + 2], acc.z);
            acc.w = fmaf(h2f(o4.w), wn[s][g * 4 + 3], acc.w);
        }
        *(float4*)&out[((size_t)(b * 64 + c)) * T_N + n0 + g * 4] = acc;
    }
}

// ---------------------------------------------------------------------------
extern "C" void kernel_launch(void* const* d_in, const int* in_sizes, int n_in,
                              void* d_out, int out_size, void* d_ws, size_t ws_size,
                              hipStream_t stream) {
    const float* x  = (const float*)d_in[0];
    const float* Wq = (const float*)d_in[1];
    const float* bq = (const float*)d_in[2];
    const float* Wk = (const float*)d_in[3];
    const float* bk = (const float*)d_in[4];
    const float* Wv = (const float*)d_in[5];
    const float* bv = (const float*)d_in[6];
    float* outp = (float*)d_out;

    const size_t elems = (size_t)T_B * T_N * T_C;
    unsigned short* qtp    = (unsigned short*)d_ws;
    unsigned short* ktp    = qtp + elems;
    unsigned short* vbuf   = ktp + elems;
    unsigned short* o_part = vbuf + elems;                       // NSLICE*elems
    float* mp = (float*)(o_part + (size_t)NSLICE * elems);
    float* lp = mp + (size_t)NSLICE * T_B * T_N;

    qkv_kernel<<<dim3(T_N / 32, T_B), 256, 0, stream>>>(
        x, Wq, bq, Wk, bk, Wv, bv, qtp, ktp, vbuf);
    attn_kernel<<<dim3(T_N / 64, NSLICE, T_B), 256, 0, stream>>>(
        qtp, ktp, vbuf, o_part, mp, lp);
    combine_kernel<<<dim3(T_N / 32, T_B), 256, 0, stream>>>(
        o_part, mp, lp, outp);
}

// Round 12
// 112.492 us; speedup vs baseline: 2.3764x; 1.3487x over previous
//
#include <hip/hip_runtime.h>
#include <math.h>

// B=4, C=64, H=W=64 -> N=4096. fp32 in/out; fp16 MFMA internally.
// R11 post-mortem: loop-carried pre[] array spilled to scratch (WRITE_SIZE
// 200MB). R12: named scalar prefetch vars, unconditional clamped loads;
// XOR-swizzled LDS layout (pitch 64 + chunk^row&7) kills the 6.3M bank
// conflicts the padded pitch-72 layout produced on b128 S reads.
// Single-fp16 Q retained (R11: absmax 0.03125, 3x margin).
#define T_N 4096
#define T_C 64
#define T_B 4
#define NSLICE 4
#define TILES_PER_SLICE (64 / NSLICE)

typedef __attribute__((ext_vector_type(8))) _Float16 f16x8;  // 4 VGPRs
typedef __attribute__((ext_vector_type(4))) _Float16 f16x4;  // 2 VGPRs
typedef __attribute__((ext_vector_type(4))) float f32x4;     // MFMA acc

__device__ inline unsigned short f2h(float f) {
    union { _Float16 h; unsigned short s; } u; u.h = (_Float16)f; return u.s;
}
__device__ inline float h2f(unsigned short s) {
    union { unsigned short s; _Float16 h; } u; u.s = s; return (float)u.h;
}

// ---------------------------------------------------------------------------
// Kernel 1: fused QKV projection via MFMA (unchanged from R11).
// grid (N/32, B) = 512 blocks, 256 thr. qt, kt: (B,N,C) fp16; vb: (B,C,N).
// ---------------------------------------------------------------------------
__global__ __launch_bounds__(256) void qkv_kernel(
    const float* __restrict__ x,
    const float* __restrict__ Wq, const float* __restrict__ bq,
    const float* __restrict__ Wk, const float* __restrict__ bk,
    const float* __restrict__ Wv, const float* __restrict__ bv,
    unsigned short* __restrict__ qt, unsigned short* __restrict__ kt,
    unsigned short* __restrict__ vb)
{
    __shared__ __align__(16) unsigned short xsh[32 * 72];   // x^T hi / bounce
    __shared__ __align__(16) unsigned short xsl[32 * 72];   // x^T lo
    __shared__ __align__(16) unsigned short wf[3][64 * 72]; // W fp16 [o][c]

    const int tid = threadIdx.x;
    const int n0  = blockIdx.x * 32;
    const int b   = blockIdx.y;
    const float* xb = x + (size_t)b * T_C * T_N;

    const float* Ws[3] = {Wq, Wk, Wv};
    #pragma unroll
    for (int p = 0; p < 3; ++p) {
        for (int i = tid; i < 1024; i += 256) {
            const int o = i >> 4, c4 = (i & 15) * 4;
            const float4 w4 = ((const float4*)Ws[p])[i];
            f16x4 wh;
            wh[0] = (_Float16)w4.x; wh[1] = (_Float16)w4.y;
            wh[2] = (_Float16)w4.z; wh[3] = (_Float16)w4.w;
            *(f16x4*)&wf[p][o * 72 + c4] = wh;
        }
    }
    for (int i = tid; i < 512; i += 256) {
        const int c = i >> 3, nj4 = (i & 7) * 4;
        const float4 xv = *(const float4*)&xb[c * T_N + n0 + nj4];
        const float xa[4] = {xv.x, xv.y, xv.z, xv.w};
        #pragma unroll
        for (int j = 0; j < 4; ++j) {
            const unsigned short h = f2h(xa[j]);
            xsh[(nj4 + j) * 72 + c] = h;
            xsl[(nj4 + j) * 72 + c] = f2h(xa[j] - h2f(h));
        }
    }
    __syncthreads();

    const int wv_  = tid >> 6;
    const int lane = tid & 63;
    const int quad = lane >> 4;
    const int col  = lane & 15;
    const int pst  = (wv_ & 1) * 16;      // pixel subtile base (0 or 16)
    const int oh   = (wv_ >> 1) * 2;      // osub base (0 or 2)
    const size_t bN = (size_t)b * T_N;

    f16x8 xh[2], xl[2];   // A[m=px][k=c]: m=col -> px = pst+col
    #pragma unroll
    for (int s = 0; s < 2; ++s) {
        xh[s] = *(const f16x8*)&xsh[(pst + col) * 72 + s * 32 + quad * 8];
        xl[s] = *(const f16x8*)&xsl[(pst + col) * 72 + s * 32 + quad * 8];
    }
    __syncthreads();   // frags in regs; xsh reusable as bounce

    const float* biases[3] = {bq, bk, bv};
    for (int p = 0; p < 3; ++p) {
        #pragma unroll
        for (int oo = 0; oo < 2; ++oo) {
            const int osub = oh + oo;
            f32x4 acc = (f32x4){0.f, 0.f, 0.f, 0.f};
            #pragma unroll
            for (int s = 0; s < 2; ++s) {
                const f16x8 wfr =   // B[k=c][n=o]: o = osub*16+col
                    *(const f16x8*)&wf[p][(osub * 16 + col) * 72 + s * 32 + quad * 8];
                acc = __builtin_amdgcn_mfma_f32_16x16x32_f16(xh[s], wfr, acc, 0, 0, 0);
                acc = __builtin_amdgcn_mfma_f32_16x16x32_f16(xl[s], wfr, acc, 0, 0, 0);
            }
            // acc[r]: px = pst+quad*4+r, o = osub*16+col
            const float bb = biases[p][osub * 16 + col];
            if (p < 2) {            // Q/K bounce [px][o] pitch 72
                #pragma unroll
                for (int r = 0; r < 4; ++r)
                    xsh[(pst + quad * 4 + r) * 72 + osub * 16 + col] = f2h(acc[r] + bb);
            } else {                // V bounce [o][px] pitch 36
                union { ushort4 v; unsigned short s[4]; } hv;
                #pragma unroll
                for (int r = 0; r < 4; ++r) hv.s[r] = f2h(acc[r] + bb);
                *(ushort4*)&xsh[(osub * 16 + col) * 36 + pst + quad * 4] = hv.v;
            }
        }
        __syncthreads();
        if (p < 2) {            // 32px x 64c: one f16x8/thread, coalesced
            const int pix = tid >> 3, c8 = (tid & 7) * 8;
            unsigned short* dst = (p == 0) ? qt : kt;
            *(f16x8*)&dst[(bN + n0 + pix) * 64 + c8] = *(const f16x8*)&xsh[pix * 72 + c8];
            __syncthreads();
        } else {                // V: 64c x 32px
            const int o = tid >> 2, p8 = (tid & 3) * 8;
            *(f16x8*)&vb[((size_t)(b * 64 + o)) * T_N + n0 + p8] =
                *(const f16x8*)&xsh[o * 36 + p8];
        }
    }
}

// ---------------------------------------------------------------------------
// Kernel 2: flash-attention partial over one key-slice.
// grid (64, NSLICE, B) = 1024 blocks, 256 thr (4 waves), LDS 16 KB.
// S^T = K*Q^T, single-fp16 Q (8 MFMAs/tile); per-lane softmax; P^T in regs.
// LDS layout: row*64 + (chunk8 ^ (row&7))*8  (XOR swizzle, conflict-free
// b128 S reads). Prefetch: 4 named float4s, unconditional clamped loads.
// ---------------------------------------------------------------------------
__global__ __launch_bounds__(256, 4) void attn_kernel(
    const unsigned short* __restrict__ qt,
    const unsigned short* __restrict__ kt, const unsigned short* __restrict__ vb,
    unsigned short* __restrict__ o_part, float* __restrict__ mp, float* __restrict__ lp)
{
    __shared__ __align__(16) unsigned short ks[64 * 64];   // [key][ch] swizzled
    __shared__ __align__(16) unsigned short vs[64 * 64];   // [ch][key] swizzled

    const int tid   = threadIdx.x;
    const int n0    = blockIdx.x * 64;
    const int slice = blockIdx.y;
    const int b     = blockIdx.z;
    const int wv_   = tid >> 6;
    const int lane  = tid & 63;
    const int quad  = lane >> 4;
    const int col   = lane & 15;

    const size_t bN = (size_t)b * T_N;
    const int q_own = n0 + wv_ * 16 + col;   // this lane's query

    f16x8 qh[2];   // B[k=ch][n=q]: n=col -> q_own
    #pragma unroll
    for (int s = 0; s < 2; ++s)
        qh[s] = *(const f16x8*)&qt[(bN + q_own) * 64 + s * 32 + quad * 8];

    // staging map: rows {row, row+32}, logical chunk cc -> physical chunk
    // cc^(row&7) ((row+32)&7 == row&7). 8 threads/row cover 128B contiguous.
    const int row = tid >> 3, cc = tid & 7;
    const int pc  = (cc ^ (row & 7)) * 8;

    const int mbase = slice * TILES_PER_SLICE * 64;
    float4 p0, p1, p2, p3;   // named scalars -> stay in VGPRs (R11 spill fix)
    p0 = *(const float4*)&kt[(bN + mbase + row) * 64 + cc * 8];
    p1 = *(const float4*)&kt[(bN + mbase + 32 + row) * 64 + cc * 8];
    p2 = *(const float4*)&vb[((size_t)(b * 64 + row)) * T_N + mbase + cc * 8];
    p3 = *(const float4*)&vb[((size_t)(b * 64 + 32 + row)) * T_N + mbase + cc * 8];

    f32x4 O[4];
    #pragma unroll
    for (int t = 0; t < 4; ++t) O[t] = (f32x4){0.f, 0.f, 0.f, 0.f};
    float m_st = -INFINITY, l_st = 0.f;

    for (int it = 0; it < TILES_PER_SLICE; ++it) {
        __syncthreads();   // previous iteration's ks/vs reads done
        *(float4*)&ks[row * 64 + pc]        = p0;
        *(float4*)&ks[(32 + row) * 64 + pc] = p1;
        *(float4*)&vs[row * 64 + pc]        = p2;
        *(float4*)&vs[(32 + row) * 64 + pc] = p3;
        __syncthreads();

        // prefetch next tile (clamped index, unconditional -> no spill)
        {
            const int itn = (it + 1 < TILES_PER_SLICE) ? it + 1 : it;
            const int m0n = mbase + itn * 64;
            p0 = *(const float4*)&kt[(bN + m0n + row) * 64 + cc * 8];
            p1 = *(const float4*)&kt[(bN + m0n + 32 + row) * 64 + cc * 8];
            p2 = *(const float4*)&vb[((size_t)(b * 64 + row)) * T_N + m0n + cc * 8];
            p3 = *(const float4*)&vb[((size_t)(b * 64 + 32 + row)) * T_N + m0n + cc * 8];
        }

        // --- S^T = K Q^T: acc[t] = S^T[key=16t+quad*4+r][q=col] ---
        f32x4 acc[4];
        #pragma unroll
        for (int t = 0; t < 4; ++t) acc[t] = (f32x4){0.f, 0.f, 0.f, 0.f};
        #pragma unroll
        for (int s = 0; s < 2; ++s) {
            #pragma unroll
            for (int t = 0; t < 4; ++t) {
                // A[m=key][k=ch]: m=col -> key=16t+col; chunk s*4+quad swizzled
                const f16x8 kf = *(const f16x8*)
                    &ks[(t * 16 + col) * 64 + (((s * 4 + quad) ^ (col & 7)) * 8)];
                acc[t] = __builtin_amdgcn_mfma_f32_16x16x32_f16(kf, qh[s], acc[t], 0, 0, 0);
            }
        }

        // --- online softmax: row = q = col; cross-quad reduce only ---
        float mx = -INFINITY;
        #pragma unroll
        for (int t = 0; t < 4; ++t)
            #pragma unroll
            for (int r = 0; r < 4; ++r) mx = fmaxf(mx, acc[t][r]);
        mx = fmaxf(mx, __shfl_xor(mx, 16));
        mx = fmaxf(mx, __shfl_xor(mx, 32));
        const float mnew = fmaxf(m_st, mx);
        const float alpha = __expf(m_st - mnew);
        float sum = 0.f;
        f16x4 pf[4];
        #pragma unroll
        for (int t = 0; t < 4; ++t) {
            #pragma unroll
            for (int r = 0; r < 4; ++r) {
                const float pv = __expf(acc[t][r] - mnew);
                sum += pv;
                pf[t][r] = (_Float16)pv;   // B[k=key=16t+quad*4+r][n=q=col]
            }
        }
        sum += __shfl_xor(sum, 16);
        sum += __shfl_xor(sum, 32);
        l_st = alpha * l_st + sum;
        m_st = mnew;

        // --- O = alpha*O + V P^T via 16x16x16 MFMA (P in registers) ---
        #pragma unroll
        for (int tc = 0; tc < 4; ++tc) {
            O[tc] *= alpha;
            #pragma unroll
            for (int t = 0; t < 4; ++t) {
                // A[m=c][k=key]: m=col -> c=tc*16+col; logical off t*16+quad*4
                const f16x4 vf = *(const f16x4*)
                    &vs[(tc * 16 + col) * 64 +
                        (((2 * t + (quad >> 1)) ^ (col & 7)) * 8) + (quad & 1) * 4];
                O[tc] = __builtin_amdgcn_mfma_f32_16x16x16f16(vf, pf[t], O[tc], 0, 0, 0);
            }
        }
    }

    // --- epilogue: O[tc][r]: c = tc*16+quad*4+r, q = col ---
    #pragma unroll
    for (int tc = 0; tc < 4; ++tc) {
        #pragma unroll
        for (int r = 0; r < 4; ++r) {
            o_part[((size_t)((slice * T_B + b) * 64 + tc * 16 + quad * 4 + r)) * T_N +
                   q_own] = f2h(O[tc][r]);
        }
    }
    if (quad == 0) {
        const size_t off = (size_t)(slice * T_B + b) * T_N + q_own;
        mp[off] = m_st;
        lp[off] = l_st;
    }
}

// ---------------------------------------------------------------------------
// Kernel 3: combine slices. grid (N/32, B), 256 thr. Pure streaming.
// ---------------------------------------------------------------------------
__global__ __launch_bounds__(256) void combine_kernel(
    const unsigned short* __restrict__ o_part,
    const float* __restrict__ mp, const float* __restrict__ lp,
    float* __restrict__ out)
{
    __shared__ float wn[NSLICE][32];

    const int tid = threadIdx.x;
    const int n0  = blockIdx.x * 32;
    const int b   = blockIdx.y;

    if (tid < 32) {
        float m_s[NSLICE], l_s[NSLICE];
        #pragma unroll
        for (int s = 0; s < NSLICE; ++s) {
            const size_t off = (size_t)(s * T_B + b) * T_N + n0 + tid;
            m_s[s] = mp[off];
            l_s[s] = lp[off];
        }
        float M = m_s[0];
        #pragma unroll
        for (int s = 1; s < NSLICE; ++s) M = fmaxf(M, m_s[s]);
        float w_s[NSLICE], L = 0.f;
        #pragma unroll
        for (int s = 0; s < NSLICE; ++s) {
            w_s[s] = __expf(m_s[s] - M);
            L += l_s[s] * w_s[s];
        }
        const float inv = 1.f / L;
        #pragma unroll
        for (int s = 0; s < NSLICE; ++s) wn[s][tid] = w_s[s] * inv;
    }
    __syncthreads();

    for (int t = tid; t < 512; t += 256) {
        const int c = t >> 3, g = t & 7;
        float4 acc = make_float4(0.f, 0.f, 0.f, 0.f);
        #pragma unroll
        for (int s = 0; s < NSLICE; ++s) {
            const ushort4 o4 = *(const ushort4*)
                &o_part[((size_t)((s * T_B + b) * 64 + c)) * T_N + n0 + g * 4];
            acc.x = fmaf(h2f(o4.x), wn[s][g * 4 + 0], acc.x);
            acc.y = fmaf(h2f(o4.y), wn[s][g * 4 + 1], acc.y);
            acc.z = fmaf(h2f(o4.z), wn[s][g * 4 + 2], acc.z);
            acc.w = fmaf(h2f(o4.w), wn[s][g * 4 + 3], acc.w);
        }
        *(float4*)&out[((size_t)(b * 64 + c)) * T_N + n0 + g * 4] = acc;
    }
}

// ---------------------------------------------------------------------------
extern "C" void kernel_launch(void* const* d_in, const int* in_sizes, int n_in,
                              void* d_out, int out_size, void* d_ws, size_t ws_size,
                              hipStream_t stream) {
    const float* x  = (const float*)d_in[0];
    const float* Wq = (const float*)d_in[1];
    const float* bq = (const float*)d_in[2];
    const float* Wk = (const float*)d_in[3];
    const float* bk = (const float*)d_in[4];
    const float* Wv = (const float*)d_in[5];
    const float* bv = (const float*)d_in[6];
    float* outp = (float*)d_out;

    const size_t elems = (size_t)T_B * T_N * T_C;
    unsigned short* qtp    = (unsigned short*)d_ws;
    unsigned short* ktp    = qtp + elems;
    unsigned short* vbuf   = ktp + elems;
    unsigned short* o_part = vbuf + elems;                       // NSLICE*elems
    float* mp = (float*)(o_part + (size_t)NSLICE * elems);
    float* lp = mp + (size_t)NSLICE * T_B * T_N;

    qkv_kernel<<<dim3(T_N / 32, T_B), 256, 0, stream>>>(
        x, Wq, bq, Wk, bk, Wv, bv, qtp, ktp, vbuf);
    attn_kernel<<<dim3(T_N / 64, NSLICE, T_B), 256, 0, stream>>>(
        qtp, ktp, vbuf, o_part, mp, lp);
    combine_kernel<<<dim3(T_N / 32, T_B), 256, 0, stream>>>(
        o_part, mp, lp, outp);
}

// Round 13
// 112.011 us; speedup vs baseline: 2.3866x; 1.0043x over previous
//
#include <hip/hip_runtime.h>
#include <math.h>

// B=4, C=64, H=W=64 -> N=4096. fp32 in/out; fp16 MFMA internally.
// R12 post-mortem: ~68us/iter is harness-fixed (256MiB ws poison fill = 44us
// + restores). attn ~40us, LDS-BW-bound (16KB read/wave/tile for 16 queries).
// R13: 2 query-fragments per wave (128-query blocks) -> every K/V LDS read
// feeds 2 MFMAs, halving LDS bytes per query. NSLICE 4->8 keeps 1024 blocks
// (4 blocks/CU). VGPR ~120 under the 128 cap; spill watch = WRITE_SIZE.
#define T_N 4096
#define T_C 64
#define T_B 4
#define NSLICE 8
#define TILES_PER_SLICE (64 / NSLICE)

typedef __attribute__((ext_vector_type(8))) _Float16 f16x8;  // 4 VGPRs
typedef __attribute__((ext_vector_type(4))) _Float16 f16x4;  // 2 VGPRs
typedef __attribute__((ext_vector_type(4))) float f32x4;     // MFMA acc

__device__ inline unsigned short f2h(float f) {
    union { _Float16 h; unsigned short s; } u; u.h = (_Float16)f; return u.s;
}
__device__ inline float h2f(unsigned short s) {
    union { unsigned short s; _Float16 h; } u; u.s = s; return (float)u.h;
}

// ---------------------------------------------------------------------------
// Kernel 1: fused QKV projection via MFMA (unchanged from R12).
// grid (N/32, B) = 512 blocks, 256 thr. qt, kt: (B,N,C) fp16; vb: (B,C,N).
// ---------------------------------------------------------------------------
__global__ __launch_bounds__(256) void qkv_kernel(
    const float* __restrict__ x,
    const float* __restrict__ Wq, const float* __restrict__ bq,
    const float* __restrict__ Wk, const float* __restrict__ bk,
    const float* __restrict__ Wv, const float* __restrict__ bv,
    unsigned short* __restrict__ qt, unsigned short* __restrict__ kt,
    unsigned short* __restrict__ vb)
{
    __shared__ __align__(16) unsigned short xsh[32 * 72];   // x^T hi / bounce
    __shared__ __align__(16) unsigned short xsl[32 * 72];   // x^T lo
    __shared__ __align__(16) unsigned short wf[3][64 * 72]; // W fp16 [o][c]

    const int tid = threadIdx.x;
    const int n0  = blockIdx.x * 32;
    const int b   = blockIdx.y;
    const float* xb = x + (size_t)b * T_C * T_N;

    const float* Ws[3] = {Wq, Wk, Wv};
    #pragma unroll
    for (int p = 0; p < 3; ++p) {
        for (int i = tid; i < 1024; i += 256) {
            const int o = i >> 4, c4 = (i & 15) * 4;
            const float4 w4 = ((const float4*)Ws[p])[i];
            f16x4 wh;
            wh[0] = (_Float16)w4.x; wh[1] = (_Float16)w4.y;
            wh[2] = (_Float16)w4.z; wh[3] = (_Float16)w4.w;
            *(f16x4*)&wf[p][o * 72 + c4] = wh;
        }
    }
    for (int i = tid; i < 512; i += 256) {
        const int c = i >> 3, nj4 = (i & 7) * 4;
        const float4 xv = *(const float4*)&xb[c * T_N + n0 + nj4];
        const float xa[4] = {xv.x, xv.y, xv.z, xv.w};
        #pragma unroll
        for (int j = 0; j < 4; ++j) {
            const unsigned short h = f2h(xa[j]);
            xsh[(nj4 + j) * 72 + c] = h;
            xsl[(nj4 + j) * 72 + c] = f2h(xa[j] - h2f(h));
        }
    }
    __syncthreads();

    const int wv_  = tid >> 6;
    const int lane = tid & 63;
    const int quad = lane >> 4;
    const int col  = lane & 15;
    const int pst  = (wv_ & 1) * 16;      // pixel subtile base (0 or 16)
    const int oh   = (wv_ >> 1) * 2;      // osub base (0 or 2)
    const size_t bN = (size_t)b * T_N;

    f16x8 xh[2], xl[2];   // A[m=px][k=c]: m=col -> px = pst+col
    #pragma unroll
    for (int s = 0; s < 2; ++s) {
        xh[s] = *(const f16x8*)&xsh[(pst + col) * 72 + s * 32 + quad * 8];
        xl[s] = *(const f16x8*)&xsl[(pst + col) * 72 + s * 32 + quad * 8];
    }
    __syncthreads();   // frags in regs; xsh reusable as bounce

    const float* biases[3] = {bq, bk, bv};
    for (int p = 0; p < 3; ++p) {
        #pragma unroll
        for (int oo = 0; oo < 2; ++oo) {
            const int osub = oh + oo;
            f32x4 acc = (f32x4){0.f, 0.f, 0.f, 0.f};
            #pragma unroll
            for (int s = 0; s < 2; ++s) {
                const f16x8 wfr =   // B[k=c][n=o]: o = osub*16+col
                    *(const f16x8*)&wf[p][(osub * 16 + col) * 72 + s * 32 + quad * 8];
                acc = __builtin_amdgcn_mfma_f32_16x16x32_f16(xh[s], wfr, acc, 0, 0, 0);
                acc = __builtin_amdgcn_mfma_f32_16x16x32_f16(xl[s], wfr, acc, 0, 0, 0);
            }
            // acc[r]: px = pst+quad*4+r, o = osub*16+col
            const float bb = biases[p][osub * 16 + col];
            if (p < 2) {            // Q/K bounce [px][o] pitch 72
                #pragma unroll
                for (int r = 0; r < 4; ++r)
                    xsh[(pst + quad * 4 + r) * 72 + osub * 16 + col] = f2h(acc[r] + bb);
            } else {                // V bounce [o][px] pitch 36
                union { ushort4 v; unsigned short s[4]; } hv;
                #pragma unroll
                for (int r = 0; r < 4; ++r) hv.s[r] = f2h(acc[r] + bb);
                *(ushort4*)&xsh[(osub * 16 + col) * 36 + pst + quad * 4] = hv.v;
            }
        }
        __syncthreads();
        if (p < 2) {            // 32px x 64c: one f16x8/thread, coalesced
            const int pix = tid >> 3, c8 = (tid & 7) * 8;
            unsigned short* dst = (p == 0) ? qt : kt;
            *(f16x8*)&dst[(bN + n0 + pix) * 64 + c8] = *(const f16x8*)&xsh[pix * 72 + c8];
            __syncthreads();
        } else {                // V: 64c x 32px
            const int o = tid >> 2, p8 = (tid & 3) * 8;
            *(f16x8*)&vb[((size_t)(b * 64 + o)) * T_N + n0 + p8] =
                *(const f16x8*)&xsh[o * 36 + p8];
        }
    }
}

// ---------------------------------------------------------------------------
// Kernel 2: flash-attention partial, 128-query blocks (2 q-frags per wave).
// grid (N/128, NSLICE, B) = 1024 blocks, 256 thr (4 waves), LDS 16 KB ->
// 4 blocks/CU. Every K/V LDS fragment read feeds TWO MFMAs (query groups
// q0 = n0+wv*32+col, q1 = q0+16) -> LDS bytes/query halved vs R12.
// XOR-swizzled LDS; named-scalar prefetch (no spill).
// ---------------------------------------------------------------------------
__global__ __launch_bounds__(256, 4) void attn_kernel(
    const unsigned short* __restrict__ qt,
    const unsigned short* __restrict__ kt, const unsigned short* __restrict__ vb,
    unsigned short* __restrict__ o_part, float* __restrict__ mp, float* __restrict__ lp)
{
    __shared__ __align__(16) unsigned short ks[64 * 64];   // [key][ch] swizzled
    __shared__ __align__(16) unsigned short vs[64 * 64];   // [ch][key] swizzled

    const int tid   = threadIdx.x;
    const int n0    = blockIdx.x * 128;
    const int slice = blockIdx.y;
    const int b     = blockIdx.z;
    const int wv_   = tid >> 6;
    const int lane  = tid & 63;
    const int quad  = lane >> 4;
    const int col   = lane & 15;

    const size_t bN = (size_t)b * T_N;
    const int q0 = n0 + wv_ * 32 + col;   // query group 0
    const int q1 = q0 + 16;               // query group 1

    f16x8 qh0[2], qh1[2];   // B[k=ch][n=q]
    #pragma unroll
    for (int s = 0; s < 2; ++s) {
        qh0[s] = *(const f16x8*)&qt[(bN + q0) * 64 + s * 32 + quad * 8];
        qh1[s] = *(const f16x8*)&qt[(bN + q1) * 64 + s * 32 + quad * 8];
    }

    // staging map: rows {row, row+32}, logical chunk cc -> physical cc^(row&7)
    const int row = tid >> 3, cc = tid & 7;
    const int pc  = (cc ^ (row & 7)) * 8;

    const int mbase = slice * TILES_PER_SLICE * 64;
    float4 p0, p1, p2, p3;   // named scalars -> stay in VGPRs
    p0 = *(const float4*)&kt[(bN + mbase + row) * 64 + cc * 8];
    p1 = *(const float4*)&kt[(bN + mbase + 32 + row) * 64 + cc * 8];
    p2 = *(const float4*)&vb[((size_t)(b * 64 + row)) * T_N + mbase + cc * 8];
    p3 = *(const float4*)&vb[((size_t)(b * 64 + 32 + row)) * T_N + mbase + cc * 8];

    f32x4 O0[4], O1[4];
    #pragma unroll
    for (int t = 0; t < 4; ++t) {
        O0[t] = (f32x4){0.f, 0.f, 0.f, 0.f};
        O1[t] = (f32x4){0.f, 0.f, 0.f, 0.f};
    }
    float m_st0 = -INFINITY, l_st0 = 0.f;
    float m_st1 = -INFINITY, l_st1 = 0.f;

    for (int it = 0; it < TILES_PER_SLICE; ++it) {
        __syncthreads();   // previous iteration's ks/vs reads done
        *(float4*)&ks[row * 64 + pc]        = p0;
        *(float4*)&ks[(32 + row) * 64 + pc] = p1;
        *(float4*)&vs[row * 64 + pc]        = p2;
        *(float4*)&vs[(32 + row) * 64 + pc] = p3;
        __syncthreads();

        // prefetch next tile (clamped index, unconditional -> no spill)
        {
            const int itn = (it + 1 < TILES_PER_SLICE) ? it + 1 : it;
            const int m0n = mbase + itn * 64;
            p0 = *(const float4*)&kt[(bN + m0n + row) * 64 + cc * 8];
            p1 = *(const float4*)&kt[(bN + m0n + 32 + row) * 64 + cc * 8];
            p2 = *(const float4*)&vb[((size_t)(b * 64 + row)) * T_N + m0n + cc * 8];
            p3 = *(const float4*)&vb[((size_t)(b * 64 + 32 + row)) * T_N + m0n + cc * 8];
        }

        // --- S^T = K Q^T: acc*[t] = S^T[key=16t+quad*4+r][q group] ---
        f32x4 acc0[4], acc1[4];
        #pragma unroll
        for (int t = 0; t < 4; ++t) {
            acc0[t] = (f32x4){0.f, 0.f, 0.f, 0.f};
            acc1[t] = (f32x4){0.f, 0.f, 0.f, 0.f};
        }
        #pragma unroll
        for (int s = 0; s < 2; ++s) {
            #pragma unroll
            for (int t = 0; t < 4; ++t) {
                const f16x8 kf = *(const f16x8*)
                    &ks[(t * 16 + col) * 64 + (((s * 4 + quad) ^ (col & 7)) * 8)];
                acc0[t] = __builtin_amdgcn_mfma_f32_16x16x32_f16(kf, qh0[s], acc0[t], 0, 0, 0);
                acc1[t] = __builtin_amdgcn_mfma_f32_16x16x32_f16(kf, qh1[s], acc1[t], 0, 0, 0);
            }
        }

        // --- online softmax, group 0 ---
        f16x4 pf0[4], pf1[4];
        float alpha0, alpha1;
        {
            float mx = -INFINITY;
            #pragma unroll
            for (int t = 0; t < 4; ++t)
                #pragma unroll
                for (int r = 0; r < 4; ++r) mx = fmaxf(mx, acc0[t][r]);
            mx = fmaxf(mx, __shfl_xor(mx, 16));
            mx = fmaxf(mx, __shfl_xor(mx, 32));
            const float mnew = fmaxf(m_st0, mx);
            alpha0 = __expf(m_st0 - mnew);
            float sum = 0.f;
            #pragma unroll
            for (int t = 0; t < 4; ++t) {
                #pragma unroll
                for (int r = 0; r < 4; ++r) {
                    const float pv = __expf(acc0[t][r] - mnew);
                    sum += pv;
                    pf0[t][r] = (_Float16)pv;
                }
            }
            sum += __shfl_xor(sum, 16);
            sum += __shfl_xor(sum, 32);
            l_st0 = alpha0 * l_st0 + sum;
            m_st0 = mnew;
        }
        // --- online softmax, group 1 ---
        {
            float mx = -INFINITY;
            #pragma unroll
            for (int t = 0; t < 4; ++t)
                #pragma unroll
                for (int r = 0; r < 4; ++r) mx = fmaxf(mx, acc1[t][r]);
            mx = fmaxf(mx, __shfl_xor(mx, 16));
            mx = fmaxf(mx, __shfl_xor(mx, 32));
            const float mnew = fmaxf(m_st1, mx);
            alpha1 = __expf(m_st1 - mnew);
            float sum = 0.f;
            #pragma unroll
            for (int t = 0; t < 4; ++t) {
                #pragma unroll
                for (int r = 0; r < 4; ++r) {
                    const float pv = __expf(acc1[t][r] - mnew);
                    sum += pv;
                    pf1[t][r] = (_Float16)pv;
                }
            }
            sum += __shfl_xor(sum, 16);
            sum += __shfl_xor(sum, 32);
            l_st1 = alpha1 * l_st1 + sum;
            m_st1 = mnew;
        }

        // --- O = alpha*O + V P^T: each vf read feeds both query groups ---
        #pragma unroll
        for (int tc = 0; tc < 4; ++tc) {
            O0[tc] *= alpha0;
            O1[tc] *= alpha1;
            #pragma unroll
            for (int t = 0; t < 4; ++t) {
                const f16x4 vf = *(const f16x4*)
                    &vs[(tc * 16 + col) * 64 +
                        (((2 * t + (quad >> 1)) ^ (col & 7)) * 8) + (quad & 1) * 4];
                O0[tc] = __builtin_amdgcn_mfma_f32_16x16x16f16(vf, pf0[t], O0[tc], 0, 0, 0);
                O1[tc] = __builtin_amdgcn_mfma_f32_16x16x16f16(vf, pf1[t], O1[tc], 0, 0, 0);
            }
        }
    }

    // --- epilogue: O*[tc][r]: c = tc*16+quad*4+r, q = q0 / q1 ---
    const size_t srow = (size_t)(slice * T_B + b) * 64;
    #pragma unroll
    for (int tc = 0; tc < 4; ++tc) {
        #pragma unroll
        for (int r = 0; r < 4; ++r) {
            const size_t crow = (srow + tc * 16 + quad * 4 + r) * T_N;
            o_part[crow + q0] = f2h(O0[tc][r]);
            o_part[crow + q1] = f2h(O1[tc][r]);
        }
    }
    if (quad == 0) {
        const size_t off = (size_t)(slice * T_B + b) * T_N;
        mp[off + q0] = m_st0;
        lp[off + q0] = l_st0;
        mp[off + q1] = m_st1;
        lp[off + q1] = l_st1;
    }
}

// ---------------------------------------------------------------------------
// Kernel 3: combine slices. grid (N/32, B), 256 thr. Pure streaming.
// ---------------------------------------------------------------------------
__global__ __launch_bounds__(256) void combine_kernel(
    const unsigned short* __restrict__ o_part,
    const float* __restrict__ mp, const float* __restrict__ lp,
    float* __restrict__ out)
{
    __shared__ float wn[NSLICE][32];

    const int tid = threadIdx.x;
    const int n0  = blockIdx.x * 32;
    const int b   = blockIdx.y;

    if (tid < 32) {
        float m_s[NSLICE], l_s[NSLICE];
        #pragma unroll
        for (int s = 0; s < NSLICE; ++s) {
            const size_t off = (size_t)(s * T_B + b) * T_N + n0 + tid;
            m_s[s] = mp[off];
            l_s[s] = lp[off];
        }
        float M = m_s[0];
        #pragma unroll
        for (int s = 1; s < NSLICE; ++s) M = fmaxf(M, m_s[s]);
        float w_s[NSLICE], L = 0.f;
        #pragma unroll
        for (int s = 0; s < NSLICE; ++s) {
            w_s[s] = __expf(m_s[s] - M);
            L += l_s[s] * w_s[s];
        }
        const float inv = 1.f / L;
        #pragma unroll
        for (int s = 0; s < NSLICE; ++s) wn[s][tid] = w_s[s] * inv;
    }
    __syncthreads();

    for (int t = tid; t < 512; t += 256) {
        const int c = t >> 3, g = t & 7;
        float4 acc = make_float4(0.f, 0.f, 0.f, 0.f);
        #pragma unroll
        for (int s = 0; s < NSLICE; ++s) {
            const ushort4 o4 = *(const ushort4*)
                &o_part[((size_t)((s * T_B + b) * 64 + c)) * T_N + n0 + g * 4];
            acc.x = fmaf(h2f(o4.x), wn[s][g * 4 + 0], acc.x);
            acc.y = fmaf(h2f(o4.y), wn[s][g * 4 + 1], acc.y);
            acc.z = fmaf(h2f(o4.z), wn[s][g * 4 + 2], acc.z);
            acc.w = fmaf(h2f(o4.w), wn[s][g * 4 + 3], acc.w);
        }
        *(float4*)&out[((size_t)(b * 64 + c)) * T_N + n0 + g * 4] = acc;
    }
}

// ---------------------------------------------------------------------------
extern "C" void kernel_launch(void* const* d_in, const int* in_sizes, int n_in,
                              void* d_out, int out_size, void* d_ws, size_t ws_size,
                              hipStream_t stream) {
    const float* x  = (const float*)d_in[0];
    const float* Wq = (const float*)d_in[1];
    const float* bq = (const float*)d_in[2];
    const float* Wk = (const float*)d_in[3];
    const float* bk = (const float*)d_in[4];
    const float* Wv = (const float*)d_in[5];
    const float* bv = (const float*)d_in[6];
    float* outp = (float*)d_out;

    const size_t elems = (size_t)T_B * T_N * T_C;
    unsigned short* qtp    = (unsigned short*)d_ws;
    unsigned short* ktp    = qtp + elems;
    unsigned short* vbuf   = ktp + elems;
    unsigned short* o_part = vbuf + elems;                       // NSLICE*elems
    float* mp = (float*)(o_part + (size_t)NSLICE * elems);
    float* lp = mp + (size_t)NSLICE * T_B * T_N;

    qkv_kernel<<<dim3(T_N / 32, T_B), 256, 0, stream>>>(
        x, Wq, bq, Wk, bk, Wv, bv, qtp, ktp, vbuf);
    attn_kernel<<<dim3(T_N / 128, NSLICE, T_B), 256, 0, stream>>>(
        qtp, ktp, vbuf, o_part, mp, lp);
    combine_kernel<<<dim3(T_N / 32, T_B), 256, 0, stream>>>(
        o_part, mp, lp, outp);
}